// Round 3
// baseline (347.062 us; speedup 1.0000x reference)
//
#include <hip/hip_runtime.h>

// CANet fused kernel, round 3.
// DTYPE FIX: reference is all-fp32 -> d_in/d_out are fp32 (t is int32).
// Internally: bf16 MFMA (threshold 2.64e-2 >> bf16 rounding at |out|<=0.2).
//
// prep_kernel: converts w1/w2/w3 fp32->bf16 into d_ws (w1 K-padded 48->64,
//   w3 O-padded 12->16), copies biases/conv weights as fp32.
// emb_kernel: 16 blocks -> emb[16][3] fp32 into d_ws float region.
// canet_main: 16384 blocks x 256 thr (4 waves); block = 64-px row segment,
//   wave = 16 px. Per wave, all through ONE per-wave LDS buffer (overlay:
//   perc stride-72 -> h1 stride-136 -> h2 stride-136; safe because within
//   each stage all A-reads precede all D-writes and same-wave LDS is
//   in-order). No inter-stage barriers. LDS ~78KB -> 2 blocks/CU.

#define ACT_S 136     // 272 B rows: 16B-aligned, 68 dwords = 4 mod 32 banks
#define PERC_S 72     // 144 B rows: 16B-aligned, 36 dwords = 4 mod 32 banks
#define W1_S 72
#define NOISE_BASE 9437184   // 16*9*65536

// d_ws layout: shorts [0, 26624): w1b[128][64] @0, w2b[128][128] @8192,
//   w3b[16][128] @24576. floats @ byte 53248: bp[48], b1[128], b2[128],
//   wp[432], emb[48].
#define WSF_OFF 13312   // float index of float region from ws base
#define WSF_BP 0
#define WSF_B1 48
#define WSF_B2 176
#define WSF_WP 304
#define WSF_EMB 736

typedef short bf16x8 __attribute__((ext_vector_type(8)));
typedef short short4v __attribute__((ext_vector_type(4)));
typedef float f32x4 __attribute__((ext_vector_type(4)));

__device__ __forceinline__ short f2bf(float f) {
    union { float f; unsigned u; } cv; cv.f = f;
    unsigned r = cv.u + 0x7FFFu + ((cv.u >> 16) & 1u);
    return (short)(r >> 16);
}

// ---------------- weight prep ----------------
__global__ void prep_kernel(const float* __restrict__ wpg, const float* __restrict__ bpg,
                            const float* __restrict__ w1g, const float* __restrict__ b1g,
                            const float* __restrict__ w2g, const float* __restrict__ b2g,
                            const float* __restrict__ w3g,
                            short* __restrict__ wsb, float* __restrict__ wsf)
{
    int i = blockIdx.x * 256 + threadIdx.x;
    if (i < 8192) {                       // w1 [128][48] -> [128][64] zero-pad
        int o = i >> 6, c = i & 63;
        wsb[i] = (c < 48) ? f2bf(w1g[o * 48 + c]) : (short)0;
    } else if (i < 24576) {               // w2 [128][128]
        wsb[i] = f2bf(w2g[i - 8192]);
    } else if (i < 26624) {               // w3 [12][128] -> [16][128] zero-pad
        int k = i - 24576;
        wsb[i] = (k < 1536) ? f2bf(w3g[k]) : (short)0;
    } else if (i < 26672) {
        wsf[WSF_BP + (i - 26624)] = bpg[i - 26624];
    } else if (i < 26800) {
        wsf[WSF_B1 + (i - 26672)] = b1g[i - 26672];
    } else if (i < 26928) {
        wsf[WSF_B2 + (i - 26800)] = b2g[i - 26800];
    } else if (i < 27360) {
        wsf[WSF_WP + (i - 26928)] = wpg[i - 26928];
    }
}

// ---------------- time-embedding ----------------
__global__ void emb_kernel(const int* __restrict__ t,
                           const float* __restrict__ wt,   // (3,256)
                           const float* __restrict__ bt,   // (3,)
                           float* __restrict__ wsf)
{
    int b = blockIdx.x;
    int lane = threadIdx.x;        // 64
    float tv = (float)t[b];
    float s0 = 0.f, s1 = 0.f, s2 = 0.f;
    const float LOG1E4 = 9.210340371976184f;
    #pragma unroll
    for (int ii = 0; ii < 2; ++ii) {
        int i = lane + ii * 64;    // 0..127
        float invf = __expf(-LOG1E4 * (float)i * (1.0f / 128.0f));
        float ang = tv * invf;
        float sn = sinf(ang), cs = cosf(ang);
        float ss = sn / (1.0f + __expf(-sn));
        float sc = cs / (1.0f + __expf(-cs));
        s0 += ss * wt[0 * 256 + i] + sc * wt[0 * 256 + i + 128];
        s1 += ss * wt[1 * 256 + i] + sc * wt[1 * 256 + i + 128];
        s2 += ss * wt[2 * 256 + i] + sc * wt[2 * 256 + i + 128];
    }
    #pragma unroll
    for (int off = 32; off; off >>= 1) {
        s0 += __shfl_down(s0, off);
        s1 += __shfl_down(s1, off);
        s2 += __shfl_down(s2, off);
    }
    if (lane == 0) {
        wsf[WSF_EMB + b * 3 + 0] = s0 + bt[0];
        wsf[WSF_EMB + b * 3 + 1] = s1 + bt[1];
        wsf[WSF_EMB + b * 3 + 2] = s2 + bt[2];
    }
}

// ---------------- main fused kernel ----------------
// A-layout: lane holds A[m=lane&15][k=q*8+j]; B: lane holds B[k=q*8+j][n=lane&15]
// (loaded as w[n][k] rows); D: col(N)=lane&15, row(M)=q*4+reg.
template<int KSTEPS, int NTILES, int ASTR, int WSTR>
__device__ __forceinline__ void gemm_tile(const short* aBuf, const short* wS,
                                          const float* bias, short* dst,
                                          int m, int q)
{
    f32x4 acc[NTILES];
    #pragma unroll
    for (int nt = 0; nt < NTILES; ++nt) {
        float bv = bias[nt * 16 + m];
        acc[nt] = {bv, bv, bv, bv};
    }
    #pragma unroll
    for (int ks = 0; ks < KSTEPS; ++ks) {
        bf16x8 a = *(const bf16x8*)(aBuf + m * ASTR + ks * 32 + q * 8);
        #pragma unroll
        for (int nt = 0; nt < NTILES; ++nt) {
            bf16x8 bw = *(const bf16x8*)(wS + (nt * 16 + m) * WSTR + ks * 32 + q * 8);
            acc[nt] = __builtin_amdgcn_mfma_f32_16x16x32_bf16(a, bw, acc[nt], 0, 0, 0);
        }
    }
    #pragma unroll
    for (int nt = 0; nt < NTILES; ++nt) {
        #pragma unroll
        for (int r = 0; r < 4; ++r) {
            dst[(q * 4 + r) * ACT_S + nt * 16 + m] = f2bf(fmaxf(acc[nt][r], 0.0f));
        }
    }
}

__global__ __launch_bounds__(256, 2) void canet_main(
    const float* __restrict__ xg,   // (16,3,256,256)
    const float* __restrict__ hg,   // (16,9,256,256)
    const short* __restrict__ wsb,  // bf16 weights
    const float* __restrict__ wsf,  // fp32 biases/conv-w/emb
    float* __restrict__ outg)       // hidden (16,9,...) then noise (16,3,...)
{
    __shared__ __align__(16) short w1s[128 * W1_S];
    __shared__ __align__(16) short w2s[128 * ACT_S];
    __shared__ __align__(16) short w3s[16 * ACT_S];
    __shared__ __align__(16) short act[4][16 * ACT_S];  // per-wave overlay buffer
    __shared__ float wp_s[48 * 9];
    __shared__ float bp_s[48];
    __shared__ float b1_s[128];
    __shared__ float b2_s[128];
    __shared__ float emb_s[3];

    const int tid = threadIdx.x;
    const int bidx = blockIdx.x;
    const int b = bidx >> 10;
    const int rem = bidx & 1023;
    const int y = rem >> 2;
    const int x0 = (rem & 3) << 6;

    // ---- stage weights (bf16x8 vector copies) ----
    for (int i = tid; i < 1024; i += 256) {          // w1: 128 rows x 8 vecs
        int o = i >> 3, v = i & 7;
        *(bf16x8*)(w1s + o * W1_S + v * 8) = *(const bf16x8*)(wsb + i * 8);
    }
    for (int i = tid; i < 2048; i += 256) {          // w2: 128 rows x 16 vecs
        int o = i >> 4, v = i & 15;
        *(bf16x8*)(w2s + o * ACT_S + v * 8) = *(const bf16x8*)(wsb + 8192 + i * 8);
    }
    for (int i = tid; i < 256; i += 256) {           // w3: 16 rows x 16 vecs
        int o = i >> 4, v = i & 15;
        *(bf16x8*)(w3s + o * ACT_S + v * 8) = *(const bf16x8*)(wsb + 24576 + i * 8);
    }
    for (int i = tid; i < 432; i += 256) wp_s[i] = wsf[WSF_WP + i];
    if (tid < 48)  bp_s[tid] = wsf[WSF_BP + tid];
    if (tid < 128) b1_s[tid] = wsf[WSF_B1 + tid];
    if (tid >= 128 && tid < 256) b2_s[tid - 128] = wsf[WSF_B2 + tid - 128];
    if (tid < 3)   emb_s[tid] = wsf[WSF_EMB + b * 3 + tid];
    __syncthreads();

    const int wv = tid >> 6;
    const int lane = tid & 63;
    const int m = lane & 15;
    const int q = lane >> 4;
    short* pA = act[wv];

    // ---- depthwise 3x3 conv (fp32) -> perc bf16 in pA (stride PERC_S) ----
    {
        const int px = x0 + wv * 16 + m;
        #pragma unroll
        for (int i3 = 0; i3 < 3; ++i3) {
            int ic = 3 * q + i3;
            const float* src = (ic < 3)
                ? (xg + (((size_t)b * 3 + ic) << 16))
                : (hg + (((size_t)b * 9 + (ic - 3)) << 16));
            float tap[9];
            #pragma unroll
            for (int ky = 0; ky < 3; ++ky) {
                int yy = y + ky - 1;
                bool yok = (yy >= 0) && (yy < 256);
                #pragma unroll
                for (int kx = 0; kx < 3; ++kx) {
                    int xx = px + kx - 1;
                    bool ok = yok && (xx >= 0) && (xx < 256);
                    tap[ky * 3 + kx] = ok ? src[yy * 256 + xx] : 0.0f;
                }
            }
            short4v pk;
            #pragma unroll
            for (int r = 0; r < 4; ++r) {
                int oc = ic * 4 + r;          // = 12q + 4*i3 + r
                float a = bp_s[oc];
                const float* wp = &wp_s[oc * 9];
                #pragma unroll
                for (int k9 = 0; k9 < 9; ++k9) a += tap[k9] * wp[k9];
                pk[r] = f2bf(a);
            }
            *(short4v*)(pA + m * PERC_S + 12 * q + 4 * i3) = pk;
        }
        *(short4v*)(pA + m * PERC_S + 48 + 4 * q) = short4v{0, 0, 0, 0};  // K pad
    }

    // ---- GEMM1: perc(16x64, stride72) x w1^T -> h1 (stride136, same buf) ----
    gemm_tile<2, 8, PERC_S, W1_S>(pA, w1s, b1_s, pA, m, q);

    // ---- GEMM2: h1 x w2^T -> h2 (overwrites h1 in place) ----
    gemm_tile<4, 8, ACT_S, ACT_S>(pA, w2s, b2_s, pA, m, q);

    // ---- GEMM3: h2 x w3^T -> out (+emb on ch 0..2), fp32 stores ----
    {
        f32x4 acc = {0.f, 0.f, 0.f, 0.f};
        #pragma unroll
        for (int ks = 0; ks < 4; ++ks) {
            bf16x8 a = *(const bf16x8*)(pA + m * ACT_S + ks * 32 + q * 8);
            bf16x8 bw = *(const bf16x8*)(w3s + m * ACT_S + ks * 32 + q * 8);
            acc = __builtin_amdgcn_mfma_f32_16x16x32_bf16(a, bw, acc, 0, 0, 0);
        }
        int oc = m;
        if (oc < 12) {
            #pragma unroll
            for (int r = 0; r < 4; ++r) {
                int p = q * 4 + r;
                int xx = x0 + wv * 16 + p;
                float v = acc[r];
                size_t idx;
                if (oc < 3) {
                    v += emb_s[oc];
                    idx = (size_t)NOISE_BASE + (((size_t)b * 3 + oc) << 16) + (size_t)y * 256 + xx;
                } else {
                    idx = (((size_t)b * 9 + (oc - 3)) << 16) + (size_t)y * 256 + xx;
                }
                outg[idx] = v;
            }
        }
    }
}

extern "C" void kernel_launch(void* const* d_in, const int* in_sizes, int n_in,
                              void* d_out, int out_size, void* d_ws, size_t ws_size,
                              hipStream_t stream) {
    const float* xg  = (const float*)d_in[0];
    const float* hg  = (const float*)d_in[1];
    const int*   tg  = (const int*)  d_in[2];
    const float* wpg = (const float*)d_in[3];
    const float* bpg = (const float*)d_in[4];
    const float* w1g = (const float*)d_in[5];
    const float* b1g = (const float*)d_in[6];
    const float* w2g = (const float*)d_in[7];
    const float* b2g = (const float*)d_in[8];
    const float* w3g = (const float*)d_in[9];
    const float* wtg = (const float*)d_in[10];
    const float* btg = (const float*)d_in[11];
    float* outg = (float*)d_out;
    short* wsb  = (short*)d_ws;
    float* wsf  = (float*)d_ws + WSF_OFF;

    prep_kernel<<<107, 256, 0, stream>>>(wpg, bpg, w1g, b1g, w2g, b2g, w3g, wsb, wsf);
    emb_kernel<<<16, 64, 0, stream>>>(tg, wtg, btg, wsf);
    canet_main<<<16384, 256, 0, stream>>>(xg, hg, wsb, wsf, outg);
}

// Round 4
// 229.713 us; speedup vs baseline: 1.5109x; 1.5109x over previous
//
#include <hip/hip_runtime.h>

// CANet fused kernel, round 4.
// Restructure vs r3 (263 us, MfmaUtil 8.7, VALU 35, Occ 23 -> latency-bound):
//  - block = one image row (4096 blocks x 256 thr), 4 iterations of 64 px:
//    weight traffic amortized 4x.
//  - wave-specialized GEMM: wave wv owns N-slice [32wv,32wv+32); B-fragments
//    for w1 (2x2), w2 (2x4), w3 (4) held in REGISTERS (64 VGPRs), loaded once
//    per block straight from global bf16 (d_ws). No weight LDS at all.
//  - activations through block-shared percS/h1S/h2S tiles (64 px), 3 barriers
//    per iteration; LDS ~47 KB -> 3 blocks/CU (12 waves/CU).
//  - prep + time-embedding merged into one launch.

#define ACT_S 136     // 272 B rows (16B-aligned) for h1/h2
#define PERC_S 72     // 144 B rows for perc (K=64 padded)
#define NOISE_BASE 9437184   // 16*9*65536

// d_ws: shorts [0,26624): w1b[128][64]@0, w2b[128][128]@8192, w3b[16][128]@24576
// floats @ WSF_OFF: bp[48], b1[128], b2[128], wp[432], emb[48]
#define WSF_OFF 13312
#define WSF_BP 0
#define WSF_B1 48
#define WSF_B2 176
#define WSF_WP 304
#define WSF_EMB 736

typedef short bf16x8 __attribute__((ext_vector_type(8)));
typedef short short4v __attribute__((ext_vector_type(4)));
typedef float f32x4 __attribute__((ext_vector_type(4)));

__device__ __forceinline__ short f2bf(float f) {
    union { float f; unsigned u; } cv; cv.f = f;
    unsigned r = cv.u + 0x7FFFu + ((cv.u >> 16) & 1u);
    return (short)(r >> 16);
}

// ---------------- weight prep + time embedding (one launch) ----------------
__global__ void prep_emb_kernel(const float* __restrict__ wpg, const float* __restrict__ bpg,
                                const float* __restrict__ w1g, const float* __restrict__ b1g,
                                const float* __restrict__ w2g, const float* __restrict__ b2g,
                                const float* __restrict__ w3g,
                                const int* __restrict__ t,
                                const float* __restrict__ wt, const float* __restrict__ bt,
                                short* __restrict__ wsb, float* __restrict__ wsf)
{
    if (blockIdx.x < 107) {
        int i = blockIdx.x * 256 + threadIdx.x;
        if (i < 8192) {                       // w1 [128][48] -> [128][64] pad
            int o = i >> 6, c = i & 63;
            wsb[i] = (c < 48) ? f2bf(w1g[o * 48 + c]) : (short)0;
        } else if (i < 24576) {               // w2 [128][128]
            wsb[i] = f2bf(w2g[i - 8192]);
        } else if (i < 26624) {               // w3 [12][128] -> [16][128] pad
            int k = i - 24576;
            wsb[i] = (k < 1536) ? f2bf(w3g[k]) : (short)0;
        } else if (i < 26672) {
            wsf[WSF_BP + (i - 26624)] = bpg[i - 26624];
        } else if (i < 26800) {
            wsf[WSF_B1 + (i - 26672)] = b1g[i - 26672];
        } else if (i < 26928) {
            wsf[WSF_B2 + (i - 26800)] = b2g[i - 26800];
        } else if (i < 27360) {
            wsf[WSF_WP + (i - 26928)] = wpg[i - 26928];
        }
        return;
    }
    // time embedding: blocks 107..122 -> b = 0..15, wave 0 only
    int b = blockIdx.x - 107;
    int lane = threadIdx.x;
    if (lane >= 64) return;
    float tv = (float)t[b];
    float s0 = 0.f, s1 = 0.f, s2 = 0.f;
    const float LOG1E4 = 9.210340371976184f;
    #pragma unroll
    for (int ii = 0; ii < 2; ++ii) {
        int i = lane + ii * 64;
        float invf = __expf(-LOG1E4 * (float)i * (1.0f / 128.0f));
        float ang = tv * invf;
        float sn = sinf(ang), cs = cosf(ang);
        float ss = sn / (1.0f + __expf(-sn));
        float sc = cs / (1.0f + __expf(-cs));
        s0 += ss * wt[0 * 256 + i] + sc * wt[0 * 256 + i + 128];
        s1 += ss * wt[1 * 256 + i] + sc * wt[1 * 256 + i + 128];
        s2 += ss * wt[2 * 256 + i] + sc * wt[2 * 256 + i + 128];
    }
    #pragma unroll
    for (int off = 32; off; off >>= 1) {
        s0 += __shfl_down(s0, off);
        s1 += __shfl_down(s1, off);
        s2 += __shfl_down(s2, off);
    }
    if (lane == 0) {
        wsf[WSF_EMB + b * 3 + 0] = s0 + bt[0];
        wsf[WSF_EMB + b * 3 + 1] = s1 + bt[1];
        wsf[WSF_EMB + b * 3 + 2] = s2 + bt[2];
    }
}

// ---------------- main fused kernel ----------------
// MFMA 16x16x32 layouts (verified m89): A lane(m,q) holds A[m][q*8+j];
// B lane(m,q) holds B[q*8+j][m] (= w[n=m][k] rows); D col=lane&15, row=q*4+r.
__global__ __launch_bounds__(256, 3) void canet_main(
    const float* __restrict__ xg,   // (16,3,256,256)
    const float* __restrict__ hg,   // (16,9,256,256)
    const short* __restrict__ wsb,  // bf16 weights
    const float* __restrict__ wsf,  // fp32 biases/conv-w/emb
    float* __restrict__ outg)
{
    __shared__ __align__(16) short percS[64 * PERC_S];  // 9.2 KB
    __shared__ __align__(16) short h1S[64 * ACT_S];     // 17.4 KB
    __shared__ __align__(16) short h2S[64 * ACT_S];     // 17.4 KB
    __shared__ float wp_s[48 * 9];
    __shared__ float bp_s[48];

    const int tid = threadIdx.x;
    const int b = blockIdx.x >> 8;
    const int y = blockIdx.x & 255;

    // conv weights/bias to LDS (broadcast-read later, conflict-free)
    for (int i = tid; i < 432; i += 256) wp_s[i] = wsf[WSF_WP + i];
    if (tid < 48) bp_s[tid] = wsf[WSF_BP + tid];

    const int wv = tid >> 6;
    const int lane = tid & 63;
    const int m = lane & 15;
    const int q = lane >> 4;

    // ---- B fragments to registers (once per block) ----
    bf16x8 w1f[2][2], w2f[2][4], w3f[4];
    #pragma unroll
    for (int j = 0; j < 2; ++j) {
        int n = wv * 32 + j * 16 + m;
        #pragma unroll
        for (int ks = 0; ks < 2; ++ks)
            w1f[j][ks] = *(const bf16x8*)(wsb + n * 64 + ks * 32 + q * 8);
        #pragma unroll
        for (int ks = 0; ks < 4; ++ks)
            w2f[j][ks] = *(const bf16x8*)(wsb + 8192 + n * 128 + ks * 32 + q * 8);
    }
    #pragma unroll
    for (int ks = 0; ks < 4; ++ks)
        w3f[ks] = *(const bf16x8*)(wsb + 24576 + m * 128 + ks * 32 + q * 8);

    const float b1v0 = wsf[WSF_B1 + wv * 32 + m];
    const float b1v1 = wsf[WSF_B1 + wv * 32 + 16 + m];
    const float b2v0 = wsf[WSF_B2 + wv * 32 + m];
    const float b2v1 = wsf[WSF_B2 + wv * 32 + 16 + m];
    const float embv = (m < 3) ? wsf[WSF_EMB + b * 3 + m] : 0.0f;

    __syncthreads();   // wp_s/bp_s ready

    for (int it = 0; it < 4; ++it) {
        const int x0 = it * 64;

        // ---- conv: wave wv computes px [x0+16wv, +16); lane does 12 oc ----
        {
            const int px = x0 + wv * 16 + m;
            short* prow = percS + (wv * 16 + m) * PERC_S;
            #pragma unroll
            for (int i3 = 0; i3 < 3; ++i3) {
                int ic = 3 * q + i3;
                const float* src = (ic < 3)
                    ? (xg + (((size_t)b * 3 + ic) << 16))
                    : (hg + (((size_t)b * 9 + (ic - 3)) << 16));
                float tap[9];
                #pragma unroll
                for (int ky = 0; ky < 3; ++ky) {
                    int yy = y + ky - 1;
                    bool yok = (yy >= 0) && (yy < 256);
                    #pragma unroll
                    for (int kx = 0; kx < 3; ++kx) {
                        int xx = px + kx - 1;
                        bool ok = yok && (xx >= 0) && (xx < 256);
                        tap[ky * 3 + kx] = ok ? src[yy * 256 + xx] : 0.0f;
                    }
                }
                short4v pk;
                #pragma unroll
                for (int r = 0; r < 4; ++r) {
                    int oc = ic * 4 + r;
                    float a = bp_s[oc];
                    const float* wp = &wp_s[oc * 9];
                    #pragma unroll
                    for (int k9 = 0; k9 < 9; ++k9) a += tap[k9] * wp[k9];
                    pk[r] = f2bf(a);
                }
                *(short4v*)(prow + 12 * q + 4 * i3) = pk;
            }
            *(short4v*)(prow + 48 + 4 * q) = short4v{0, 0, 0, 0};
        }
        __syncthreads();

        // ---- GEMM1: perc(64x64) x w1^T -> h1 slice [*, 32wv..32wv+32) ----
        #pragma unroll
        for (int mb = 0; mb < 4; ++mb) {
            f32x4 a0 = {b1v0, b1v0, b1v0, b1v0};
            f32x4 a1 = {b1v1, b1v1, b1v1, b1v1};
            #pragma unroll
            for (int ks = 0; ks < 2; ++ks) {
                bf16x8 a = *(const bf16x8*)(percS + (mb * 16 + m) * PERC_S + ks * 32 + q * 8);
                a0 = __builtin_amdgcn_mfma_f32_16x16x32_bf16(a, w1f[0][ks], a0, 0, 0, 0);
                a1 = __builtin_amdgcn_mfma_f32_16x16x32_bf16(a, w1f[1][ks], a1, 0, 0, 0);
            }
            #pragma unroll
            for (int r = 0; r < 4; ++r) {
                int row = mb * 16 + q * 4 + r;
                h1S[row * ACT_S + wv * 32 + m]      = f2bf(fmaxf(a0[r], 0.0f));
                h1S[row * ACT_S + wv * 32 + 16 + m] = f2bf(fmaxf(a1[r], 0.0f));
            }
        }
        __syncthreads();

        // ---- GEMM2: h1(64x128) x w2^T -> h2 slice ----
        #pragma unroll
        for (int mb = 0; mb < 4; ++mb) {
            f32x4 a0 = {b2v0, b2v0, b2v0, b2v0};
            f32x4 a1 = {b2v1, b2v1, b2v1, b2v1};
            #pragma unroll
            for (int ks = 0; ks < 4; ++ks) {
                bf16x8 a = *(const bf16x8*)(h1S + (mb * 16 + m) * ACT_S + ks * 32 + q * 8);
                a0 = __builtin_amdgcn_mfma_f32_16x16x32_bf16(a, w2f[0][ks], a0, 0, 0, 0);
                a1 = __builtin_amdgcn_mfma_f32_16x16x32_bf16(a, w2f[1][ks], a1, 0, 0, 0);
            }
            #pragma unroll
            for (int r = 0; r < 4; ++r) {
                int row = mb * 16 + q * 4 + r;
                h2S[row * ACT_S + wv * 32 + m]      = f2bf(fmaxf(a0[r], 0.0f));
                h2S[row * ACT_S + wv * 32 + 16 + m] = f2bf(fmaxf(a1[r], 0.0f));
            }
        }
        __syncthreads();

        // ---- GEMM3: own 16-px block (mb=wv) x w3^T -> out + emb ----
        {
            f32x4 acc = {0.f, 0.f, 0.f, 0.f};
            #pragma unroll
            for (int ks = 0; ks < 4; ++ks) {
                bf16x8 a = *(const bf16x8*)(h2S + (wv * 16 + m) * ACT_S + ks * 32 + q * 8);
                acc = __builtin_amdgcn_mfma_f32_16x16x32_bf16(a, w3f[ks], acc, 0, 0, 0);
            }
            if (m < 12) {
                #pragma unroll
                for (int r = 0; r < 4; ++r) {
                    int xx = x0 + wv * 16 + q * 4 + r;
                    float v = acc[r];
                    size_t idx;
                    if (m < 3) {
                        v += embv;
                        idx = (size_t)NOISE_BASE + (((size_t)b * 3 + m) << 16) + (size_t)y * 256 + xx;
                    } else {
                        idx = (((size_t)b * 9 + (m - 3)) << 16) + (size_t)y * 256 + xx;
                    }
                    outg[idx] = v;
                }
            }
        }
        // next-iter conv writes percS: safe, all waves passed GEMM1 reads
        // (ordering enforced by this iteration's barriers).
    }
}

extern "C" void kernel_launch(void* const* d_in, const int* in_sizes, int n_in,
                              void* d_out, int out_size, void* d_ws, size_t ws_size,
                              hipStream_t stream) {
    const float* xg  = (const float*)d_in[0];
    const float* hg  = (const float*)d_in[1];
    const int*   tg  = (const int*)  d_in[2];
    const float* wpg = (const float*)d_in[3];
    const float* bpg = (const float*)d_in[4];
    const float* w1g = (const float*)d_in[5];
    const float* b1g = (const float*)d_in[6];
    const float* w2g = (const float*)d_in[7];
    const float* b2g = (const float*)d_in[8];
    const float* w3g = (const float*)d_in[9];
    const float* wtg = (const float*)d_in[10];
    const float* btg = (const float*)d_in[11];
    float* outg = (float*)d_out;
    short* wsb  = (short*)d_ws;
    float* wsf  = (float*)d_ws + WSF_OFF;

    prep_emb_kernel<<<123, 256, 0, stream>>>(wpg, bpg, w1g, b1g, w2g, b2g, w3g,
                                             tg, wtg, btg, wsb, wsf);
    canet_main<<<4096, 256, 0, stream>>>(xg, hg, wsb, wsf, outg);
}

// Round 5
// 226.757 us; speedup vs baseline: 1.5305x; 1.0130x over previous
//
#include <hip/hip_runtime.h>

// CANet fused kernel, round 5.
// vs r4 (144 us, MfmaUtil 16, VALU 45): cut VALU-issue cost.
//  - GEMM1/2 operand-swapped (A=weights in regs, B=activations^T from LDS;
//    16x16x32 A/B lane layouts are symmetric so same register arrangement
//    serves either role). D then gives each lane 4 consecutive CHANNELS of
//    one pixel -> pack 4 bf16 -> single ds_write_b64 into [px][ch] rows,
//    which is exactly the next stage's B-read layout. Bias = float4 vector.
//  - f2bf via round-half-up + v_perm pack (3 ops / 2 values).
//  - conv: interior-row fast path (clamped addr + 2 x-masks), src pointers
//    hoisted out of the pixel loop, weights padded to 12/row for float4 reads.
//  - GEMM3 emits one float4 global store per lane.

#define ACT_S 136     // 272 B rows (16B-aligned) for h1/h2 [px][ch]
#define PERC_S 72     // 144 B rows for perc [px][ch48->64]
#define NOISE_BASE 9437184   // 16*9*65536

// d_ws: shorts [0,26624): w1b[128][64]@0, w2b[128][128]@8192, w3b[16][128]@24576
// floats @ WSF_OFF: bp[48], b1[128], b2[128], wp[432], emb[48]
#define WSF_OFF 13312
#define WSF_BP 0
#define WSF_B1 48
#define WSF_B2 176
#define WSF_WP 304
#define WSF_EMB 736

typedef short bf16x8 __attribute__((ext_vector_type(8)));
typedef float f32x4 __attribute__((ext_vector_type(4)));

__device__ __forceinline__ short f2bf(float f) {
    union { float f; unsigned u; } cv; cv.f = f;
    unsigned r = cv.u + 0x7FFFu + ((cv.u >> 16) & 1u);
    return (short)(r >> 16);
}
// pack two fp32 -> dword of two bf16 (round-half-up): lo16=bf(f0), hi16=bf(f1)
__device__ __forceinline__ unsigned pk2bf(float f0, float f1) {
    union { float f; unsigned u; } a, b; a.f = f0; b.f = f1;
    return __builtin_amdgcn_perm(b.u + 0x8000u, a.u + 0x8000u, 0x07060302u);
}

// ---------------- weight prep + time embedding (one launch) ----------------
__global__ void prep_emb_kernel(const float* __restrict__ wpg, const float* __restrict__ bpg,
                                const float* __restrict__ w1g, const float* __restrict__ b1g,
                                const float* __restrict__ w2g, const float* __restrict__ b2g,
                                const float* __restrict__ w3g,
                                const int* __restrict__ t,
                                const float* __restrict__ wt, const float* __restrict__ bt,
                                short* __restrict__ wsb, float* __restrict__ wsf)
{
    if (blockIdx.x < 107) {
        int i = blockIdx.x * 256 + threadIdx.x;
        if (i < 8192) {                       // w1 [128][48] -> [128][64] pad
            int o = i >> 6, c = i & 63;
            wsb[i] = (c < 48) ? f2bf(w1g[o * 48 + c]) : (short)0;
        } else if (i < 24576) {               // w2 [128][128]
            wsb[i] = f2bf(w2g[i - 8192]);
        } else if (i < 26624) {               // w3 [12][128] -> [16][128] pad
            int k = i - 24576;
            wsb[i] = (k < 1536) ? f2bf(w3g[k]) : (short)0;
        } else if (i < 26672) {
            wsf[WSF_BP + (i - 26624)] = bpg[i - 26624];
        } else if (i < 26800) {
            wsf[WSF_B1 + (i - 26672)] = b1g[i - 26672];
        } else if (i < 26928) {
            wsf[WSF_B2 + (i - 26800)] = b2g[i - 26800];
        } else if (i < 27360) {
            wsf[WSF_WP + (i - 26928)] = wpg[i - 26928];
        }
        return;
    }
    int b = blockIdx.x - 107;
    int lane = threadIdx.x;
    if (lane >= 64) return;
    float tv = (float)t[b];
    float s0 = 0.f, s1 = 0.f, s2 = 0.f;
    const float LOG1E4 = 9.210340371976184f;
    #pragma unroll
    for (int ii = 0; ii < 2; ++ii) {
        int i = lane + ii * 64;
        float invf = __expf(-LOG1E4 * (float)i * (1.0f / 128.0f));
        float ang = tv * invf;
        float sn = sinf(ang), cs = cosf(ang);
        float ss = sn / (1.0f + __expf(-sn));
        float sc = cs / (1.0f + __expf(-cs));
        s0 += ss * wt[0 * 256 + i] + sc * wt[0 * 256 + i + 128];
        s1 += ss * wt[1 * 256 + i] + sc * wt[1 * 256 + i + 128];
        s2 += ss * wt[2 * 256 + i] + sc * wt[2 * 256 + i + 128];
    }
    #pragma unroll
    for (int off = 32; off; off >>= 1) {
        s0 += __shfl_down(s0, off);
        s1 += __shfl_down(s1, off);
        s2 += __shfl_down(s2, off);
    }
    if (lane == 0) {
        wsf[WSF_EMB + b * 3 + 0] = s0 + bt[0];
        wsf[WSF_EMB + b * 3 + 1] = s1 + bt[1];
        wsf[WSF_EMB + b * 3 + 2] = s2 + bt[2];
    }
}

// ---------------- main fused kernel ----------------
// MFMA 16x16x32 (m89): A lane(i=lane&15,q) holds A[i][q*8+j]; B symmetric:
// lane holds B[q*8+j][i]. D: col(N)=lane&15, row(M)=q*4+r.
__global__ __launch_bounds__(256, 3) void canet_main(
    const float* __restrict__ xg,   // (16,3,256,256)
    const float* __restrict__ hg,   // (16,9,256,256)
    const short* __restrict__ wsb,
    const float* __restrict__ wsf,
    float* __restrict__ outg)
{
    __shared__ __align__(16) short percS[64 * PERC_S];
    __shared__ __align__(16) short h1S[64 * ACT_S];
    __shared__ __align__(16) short h2S[64 * ACT_S];
    __shared__ __align__(16) float wp_s[48 * 12];   // 9 taps padded to 12
    __shared__ float bp_s[48];

    const int tid = threadIdx.x;
    const int b = blockIdx.x >> 8;
    const int y = blockIdx.x & 255;

    for (int i = tid; i < 576; i += 256) {
        int oc = i / 12, k = i % 12;
        wp_s[i] = (k < 9) ? wsf[WSF_WP + oc * 9 + k] : 0.0f;
    }
    if (tid < 48) bp_s[tid] = wsf[WSF_BP + tid];

    const int wv = tid >> 6;
    const int lane = tid & 63;
    const int m = lane & 15;
    const int q = lane >> 4;

    // ---- weight fragments to registers (once per block) ----
    bf16x8 w1f[2][2], w2f[2][4], w3f[4];
    #pragma unroll
    for (int j = 0; j < 2; ++j) {
        int n = wv * 32 + j * 16 + m;
        #pragma unroll
        for (int ks = 0; ks < 2; ++ks)
            w1f[j][ks] = *(const bf16x8*)(wsb + n * 64 + ks * 32 + q * 8);
        #pragma unroll
        for (int ks = 0; ks < 4; ++ks)
            w2f[j][ks] = *(const bf16x8*)(wsb + 8192 + n * 128 + ks * 32 + q * 8);
    }
    #pragma unroll
    for (int ks = 0; ks < 4; ++ks)
        w3f[ks] = *(const bf16x8*)(wsb + 24576 + m * 128 + ks * 32 + q * 8);

    // bias vectors: D rows = channels (wv*32 + j*16 + q*4 + r)
    f32x4 b1v[2], b2v[2];
    #pragma unroll
    for (int j = 0; j < 2; ++j) {
        b1v[j] = *(const f32x4*)(wsf + WSF_B1 + wv * 32 + j * 16 + q * 4);
        b2v[j] = *(const f32x4*)(wsf + WSF_B2 + wv * 32 + j * 16 + q * 4);
    }
    const float embv = (m < 3) ? wsf[WSF_EMB + b * 3 + m] : 0.0f;

    // conv source pointers (lane's 3 input channels: ic = 3q + i3)
    const float* src3[3];
    #pragma unroll
    for (int i3 = 0; i3 < 3; ++i3) {
        int ic = 3 * q + i3;
        src3[i3] = (ic < 3) ? (xg + (((size_t)b * 3 + ic) << 16))
                            : (hg + (((size_t)b * 9 + (ic - 3)) << 16));
    }

    __syncthreads();   // wp_s/bp_s ready

    for (int it = 0; it < 4; ++it) {
        const int x0 = it * 64;
        const int px = x0 + wv * 16 + m;

        // ---- depthwise 3x3 conv -> percS[px][ch] ----
        {
            const int xm1 = px - (px > 0);
            const int xp1 = px + (px < 255);
            const bool okl = (px > 0), okr = (px < 255);
            short* prow = percS + (wv * 16 + m) * PERC_S;
            const bool interior = (y >= 1) && (y <= 254);
            #pragma unroll
            for (int i3 = 0; i3 < 3; ++i3) {
                const float* s = src3[i3];
                float tap[9];
                if (interior) {
                    #pragma unroll
                    for (int ky = 0; ky < 3; ++ky) {
                        const float* rp = s + (y + ky - 1) * 256;
                        float c0 = rp[xm1], c1 = rp[px], c2 = rp[xp1];
                        tap[ky * 3 + 0] = okl ? c0 : 0.0f;
                        tap[ky * 3 + 1] = c1;
                        tap[ky * 3 + 2] = okr ? c2 : 0.0f;
                    }
                } else {
                    #pragma unroll
                    for (int ky = 0; ky < 3; ++ky) {
                        int yy = y + ky - 1;
                        bool yok = (yy >= 0) && (yy < 256);
                        const float* rp = s + (yok ? yy : y) * 256;
                        float c0 = rp[xm1], c1 = rp[px], c2 = rp[xp1];
                        tap[ky * 3 + 0] = (yok && okl) ? c0 : 0.0f;
                        tap[ky * 3 + 1] = yok ? c1 : 0.0f;
                        tap[ky * 3 + 2] = (yok && okr) ? c2 : 0.0f;
                    }
                }
                float v[4];
                #pragma unroll
                for (int r = 0; r < 4; ++r) {
                    int oc = 12 * q + 4 * i3 + r;
                    const float* wrow = &wp_s[oc * 12];
                    f32x4 w0 = *(const f32x4*)wrow;
                    f32x4 w1_ = *(const f32x4*)(wrow + 4);
                    float a = bp_s[oc];
                    a += w0[0] * tap[0] + w0[1] * tap[1] + w0[2] * tap[2] + w0[3] * tap[3];
                    a += w1_[0] * tap[4] + w1_[1] * tap[5] + w1_[2] * tap[6] + w1_[3] * tap[7];
                    a += wrow[8] * tap[8];
                    v[r] = a;
                }
                uint2 pk;
                pk.x = pk2bf(v[0], v[1]);
                pk.y = pk2bf(v[2], v[3]);
                *(uint2*)(prow + 12 * q + 4 * i3) = pk;
            }
            *(uint2*)(prow + 48 + 4 * q) = uint2{0u, 0u};   // K pad 48..63
        }
        __syncthreads();

        // ---- GEMM1 (swapped): D[ch][px] = w1 . perc^T ; write h1S[px][ch] ----
        #pragma unroll
        for (int nt = 0; nt < 4; ++nt) {
            f32x4 c0 = b1v[0], c1 = b1v[1];
            #pragma unroll
            for (int ks = 0; ks < 2; ++ks) {
                bf16x8 p = *(const bf16x8*)(percS + (nt * 16 + m) * PERC_S + ks * 32 + q * 8);
                c0 = __builtin_amdgcn_mfma_f32_16x16x32_bf16(w1f[0][ks], p, c0, 0, 0, 0);
                c1 = __builtin_amdgcn_mfma_f32_16x16x32_bf16(w1f[1][ks], p, c1, 0, 0, 0);
            }
            short* drow = h1S + (nt * 16 + m) * ACT_S + wv * 32 + q * 4;
            uint2 pk;
            pk.x = pk2bf(fmaxf(c0[0], 0.f), fmaxf(c0[1], 0.f));
            pk.y = pk2bf(fmaxf(c0[2], 0.f), fmaxf(c0[3], 0.f));
            *(uint2*)drow = pk;
            pk.x = pk2bf(fmaxf(c1[0], 0.f), fmaxf(c1[1], 0.f));
            pk.y = pk2bf(fmaxf(c1[2], 0.f), fmaxf(c1[3], 0.f));
            *(uint2*)(drow + 16) = pk;
        }
        __syncthreads();

        // ---- GEMM2 (swapped): D[ch][px] = w2 . h1^T ; write h2S[px][ch] ----
        #pragma unroll
        for (int nt = 0; nt < 4; ++nt) {
            f32x4 c0 = b2v[0], c1 = b2v[1];
            #pragma unroll
            for (int ks = 0; ks < 4; ++ks) {
                bf16x8 a = *(const bf16x8*)(h1S + (nt * 16 + m) * ACT_S + ks * 32 + q * 8);
                c0 = __builtin_amdgcn_mfma_f32_16x16x32_bf16(w2f[0][ks], a, c0, 0, 0, 0);
                c1 = __builtin_amdgcn_mfma_f32_16x16x32_bf16(w2f[1][ks], a, c1, 0, 0, 0);
            }
            short* drow = h2S + (nt * 16 + m) * ACT_S + wv * 32 + q * 4;
            uint2 pk;
            pk.x = pk2bf(fmaxf(c0[0], 0.f), fmaxf(c0[1], 0.f));
            pk.y = pk2bf(fmaxf(c0[2], 0.f), fmaxf(c0[3], 0.f));
            *(uint2*)drow = pk;
            pk.x = pk2bf(fmaxf(c1[0], 0.f), fmaxf(c1[1], 0.f));
            pk.y = pk2bf(fmaxf(c1[2], 0.f), fmaxf(c1[3], 0.f));
            *(uint2*)(drow + 16) = pk;
        }
        __syncthreads();

        // ---- GEMM3: out = h2 . w3^T ; D col=oc, row=px; float4 store ----
        {
            f32x4 acc = {0.f, 0.f, 0.f, 0.f};
            #pragma unroll
            for (int ks = 0; ks < 4; ++ks) {
                bf16x8 a = *(const bf16x8*)(h2S + (wv * 16 + m) * ACT_S + ks * 32 + q * 8);
                acc = __builtin_amdgcn_mfma_f32_16x16x32_bf16(a, w3f[ks], acc, 0, 0, 0);
            }
            if (m < 12) {
                int xx0 = x0 + wv * 16 + q * 4;
                size_t idx;
                if (m < 3) {
                    idx = (size_t)NOISE_BASE + (((size_t)b * 3 + m) << 16) + (size_t)y * 256 + xx0;
                } else {
                    idx = (((size_t)b * 9 + (m - 3)) << 16) + (size_t)y * 256 + xx0;
                }
                f32x4 vst = {acc[0] + embv, acc[1] + embv, acc[2] + embv, acc[3] + embv};
                *(f32x4*)(outg + idx) = vst;
            }
        }
        // next-iter conv writes percS only after this iter's GEMM1 barrier.
    }
}

extern "C" void kernel_launch(void* const* d_in, const int* in_sizes, int n_in,
                              void* d_out, int out_size, void* d_ws, size_t ws_size,
                              hipStream_t stream) {
    const float* xg  = (const float*)d_in[0];
    const float* hg  = (const float*)d_in[1];
    const int*   tg  = (const int*)  d_in[2];
    const float* wpg = (const float*)d_in[3];
    const float* bpg = (const float*)d_in[4];
    const float* w1g = (const float*)d_in[5];
    const float* b1g = (const float*)d_in[6];
    const float* w2g = (const float*)d_in[7];
    const float* b2g = (const float*)d_in[8];
    const float* w3g = (const float*)d_in[9];
    const float* wtg = (const float*)d_in[10];
    const float* btg = (const float*)d_in[11];
    float* outg = (float*)d_out;
    short* wsb  = (short*)d_ws;
    float* wsf  = (float*)d_ws + WSF_OFF;

    prep_emb_kernel<<<123, 256, 0, stream>>>(wpg, bpg, w1g, b1g, w2g, b2g, w3g,
                                             tg, wtg, btg, wsb, wsf);
    canet_main<<<4096, 256, 0, stream>>>(xg, hg, wsb, wsf, outg);
}